// Round 8
// baseline (1310.430 us; speedup 1.0000x reference)
//
#include <hip/hip_runtime.h>

#define DEV __device__ __forceinline__

typedef __bf16 bf16x8 __attribute__((ext_vector_type(8)));
typedef float  f32x4  __attribute__((ext_vector_type(4)));

DEV float b2f(unsigned short u) {
    unsigned int t = ((unsigned int)u) << 16;
    return __uint_as_float(t);
}
DEV unsigned short f2b(float f) {
    unsigned int u = __float_as_uint(f);
    unsigned int r = (u + 0x7FFFu + ((u >> 16) & 1u)) >> 16;
    return (unsigned short)r;
}

DEV void gload_lds16(const unsigned short* g, unsigned short* l) {
    __builtin_amdgcn_global_load_lds(
        (const __attribute__((address_space(1))) void*)(const void*)g,
        (__attribute__((address_space(3))) void*)(void*)l, 16, 0, 0);
}

// dest window-row -> source/dest token index (roll by SS=3, window 7x7, 56x56, 64 win/batch)
DEV size_t win_to_tok(int row) {
    int w = row / 49, t = row - w * 49;
    int b  = w >> 6, widx = w & 63;
    int wi = widx >> 3, wj = widx & 7;
    int ti = t / 7, tj = t - ti * 7;
    int hh = wi * 7 + ti + 3; if (hh >= 56) hh -= 56;
    int ww = wj * 7 + tj + 3; if (ww >= 56) ww -= 56;
    return (size_t)b * 3136 + (size_t)hh * 56 + ww;
}

// ---------------- weight prep: fp32 [K][N] -> bf16 [N][K] ----------------
__global__ void wprep(const float* __restrict__ src, unsigned short* __restrict__ dst,
                      int K, int N) {
    int idx = blockIdx.x * 256 + threadIdx.x;
    if (idx >= K * N) return;
    int k = idx / N, n = idx - k * N;
    dst[(size_t)n * K + k] = f2b(src[idx]);
}

// ---------------- LayerNorm (+optional shifted-window gather), fp32 -> bf16 ----------------
template <int REMAP>
__global__ __launch_bounds__(256) void ln_kernel(const float* __restrict__ x,
                                                 const float* __restrict__ g,
                                                 const float* __restrict__ b,
                                                 unsigned short* __restrict__ out,
                                                 int rows) {
    int r = blockIdx.x * 4 + (threadIdx.x >> 6);
    int lane = threadIdx.x & 63;
    if (r >= rows) return;
    size_t src = REMAP ? win_to_tok(r) : (size_t)r;
    const float* xp = x + src * 384;
    float v[6];
    float s = 0.f;
#pragma unroll
    for (int i = 0; i < 6; ++i) { v[i] = xp[i * 64 + lane]; s += v[i]; }
#pragma unroll
    for (int off = 32; off; off >>= 1) s += __shfl_xor(s, off, 64);
    float mu = s * (1.f / 384.f);
    float q = 0.f;
#pragma unroll
    for (int i = 0; i < 6; ++i) { float d = v[i] - mu; q += d * d; }
#pragma unroll
    for (int off = 32; off; off >>= 1) q += __shfl_xor(q, off, 64);
    float inv = rsqrtf(q * (1.f / 384.f) + 1e-5f);
    unsigned short* op = out + (size_t)r * 384;
#pragma unroll
    for (int i = 0; i < 6; ++i) {
        int c = i * 64 + lane;
        op[c] = f2b((v[i] - mu) * inv * g[c] + b[c]);
    }
}

// ---------------- GEMM: C[M][N] = A[M][K] (bf16, row-major) x Bt[N][K] (bf16) ----------------
// 8-phase-style schedule (m201-mini): BM=256 x BN=128 x BK=64, 8 waves (4M x 2N),
// 3-buffer LDS ring (144 KB), 2-tile lookahead, counted vmcnt (6, never 0 in steady state),
// 2 phases per K-tile each {stage-half || ds_read cluster -> barrier -> lgkmcnt(0) ->
// setprio(1) 16xMFMA setprio(0) -> barrier}. LDS XOR swizzle (slot ^= row&7) applied
// both-sides: pre-swizzled global source (gload_lds writes linearly) + swizzled ds_read.
// MODE 0: out bf16 = C                               (QKV)
// MODE 1: h[tok] = x[tok] + C + bias  (un-window+un-roll remap, fp32 out)   (proj)
// MODE 2: out bf16 = gelu(C + bias)   (tanh-form)    (FFN1)
// MODE 3: outf = resid + C + bias  (resid may alias outf)                   (FFN2)
template <int MODE>
__global__ __launch_bounds__(512, 2) void gemm_kernel(const unsigned short* __restrict__ A,
                                                      const unsigned short* __restrict__ Bt,
                                                      int M, int N, int K,
                                                      const float* __restrict__ bias,
                                                      const float* __restrict__ resid,
                                                      unsigned short* __restrict__ outb,
                                                      float* __restrict__ outf) {
    __shared__ unsigned short As[3 * 256 * 64];   // 96 KB
    __shared__ unsigned short Bs[3 * 128 * 64];   // 48 KB
    const int tid = threadIdx.x;
    const int wid = tid >> 6, lane = tid & 63;
    const int ntile = N >> 7;

    // XCD-aware block swizzle (grid % 8 == 0 for all our launches)
    int bid = blockIdx.x;
    int nwg = gridDim.x;
    int swb = ((nwg & 7) == 0) ? ((bid & 7) * (nwg >> 3) + (bid >> 3)) : bid;
    const int mt = swb / ntile, nt = swb - mt * ntile;
    const int wr = wid >> 1, wc = wid & 1;   // 4 wave-rows x 2 wave-cols

    f32x4 acc[4][4] = {};

    const unsigned short* Abase = A  + (size_t)(mt * 256) * K;
    const unsigned short* Bbase = Bt + (size_t)(nt * 128) * K;

    // staging: thread writes LDS linearly at byte tid*16 within an 8KB chunk;
    // physical (row, slot) holds logical k-chunk slot ^ (row&7)  -> fetch that chunk.
    const int srow = tid >> 3;                       // 0..63 within chunk
    const int skc  = (tid & 7) ^ ((tid >> 3) & 7);   // pre-swizzled global k-chunk

    auto stageA = [&](int buf, int k0, int c) {      // c = 0..3 (64 rows each)
        int row = c * 64 + srow;
        gload_lds16(Abase + (size_t)row * K + k0 + skc * 8,
                    &As[buf * 16384 + c * 4096 + tid * 8]);
    };
    auto stageB = [&](int buf, int k0, int c) {      // c = 0..1
        int row = c * 64 + srow;
        gload_lds16(Bbase + (size_t)row * K + k0 + skc * 8,
                    &Bs[buf * 8192 + c * 4096 + tid * 8]);
    };
    auto stage_h = [&](int buf, int k0, int h) {     // 3 loads per half
        if (h == 0) { stageA(buf, k0, 0); stageA(buf, k0, 1); stageB(buf, k0, 0); }
        else        { stageA(buf, k0, 2); stageA(buf, k0, 3); stageB(buf, k0, 1); }
    };

    // fragment reads: logical (row, kchunk) at physical slot = kchunk ^ (row&7)
    const int arow = wr * 64 + (lane & 15);
    const int brow = wc * 64 + (lane & 15);
    const int kq   = lane >> 4;                      // k-quarter 0..3
    auto ldA = [&](int buf, int m, int ks) {
        int row  = arow + m * 16;
        int slot = (ks * 4 + kq) ^ (row & 7);
        return *(const bf16x8*)&As[buf * 16384 + row * 64 + slot * 8];
    };
    auto ldB = [&](int buf, int n, int ks) {
        int row  = brow + n * 16;
        int slot = (ks * 4 + kq) ^ (row & 7);
        return *(const bf16x8*)&Bs[buf * 8192 + row * 64 + slot * 8];
    };

    const int nk = K >> 6;   // K-tiles of 64 (K=384 -> 6, K=1536 -> 24)
    stage_h(0, 0, 0);  stage_h(0, 0, 1);
    stage_h(1, 64, 0); stage_h(1, 64, 1);
    asm volatile("s_waitcnt vmcnt(6)" ::: "memory");   // tile 0 landed (own)
    __builtin_amdgcn_s_barrier();                      // tile 0 landed (all waves)

    for (int t = 0; t < nk; ++t) {
        const int cur = t % 3, nxt = (t + 2) % 3;
        const bool pf = (t + 2 < nk);
        bf16x8 a[2][2], b[4][2], a2[2][2];

        // ---- phase 0: C rows m{0,1} ----
        if (pf) stage_h(nxt, (t + 2) << 6, 0);
#pragma unroll
        for (int m = 0; m < 2; ++m) { a[m][0] = ldA(cur, m, 0); a[m][1] = ldA(cur, m, 1); }
#pragma unroll
        for (int n = 0; n < 4; ++n) { b[n][0] = ldB(cur, n, 0); b[n][1] = ldB(cur, n, 1); }
        __builtin_amdgcn_s_barrier();
        asm volatile("s_waitcnt lgkmcnt(0)" ::: "memory");
        __builtin_amdgcn_sched_barrier(0);
        __builtin_amdgcn_s_setprio(1);
#pragma unroll
        for (int ks = 0; ks < 2; ++ks)
#pragma unroll
            for (int m = 0; m < 2; ++m)
#pragma unroll
                for (int n = 0; n < 4; ++n)
                    acc[m][n] = __builtin_amdgcn_mfma_f32_16x16x32_bf16(a[m][ks], b[n][ks], acc[m][n], 0, 0, 0);
        __builtin_amdgcn_s_setprio(0);
        __builtin_amdgcn_s_barrier();

        // ---- phase 1: C rows m{2,3} ----
        if (pf) stage_h(nxt, (t + 2) << 6, 1);
#pragma unroll
        for (int m = 0; m < 2; ++m) { a2[m][0] = ldA(cur, m + 2, 0); a2[m][1] = ldA(cur, m + 2, 1); }
        __builtin_amdgcn_s_barrier();
        asm volatile("s_waitcnt lgkmcnt(0)" ::: "memory");
        __builtin_amdgcn_sched_barrier(0);
        __builtin_amdgcn_s_setprio(1);
#pragma unroll
        for (int ks = 0; ks < 2; ++ks)
#pragma unroll
            for (int m = 0; m < 2; ++m)
#pragma unroll
                for (int n = 0; n < 4; ++n)
                    acc[m + 2][n] = __builtin_amdgcn_mfma_f32_16x16x32_bf16(a2[m][ks], b[n][ks], acc[m + 2][n], 0, 0, 0);
        __builtin_amdgcn_s_setprio(0);
        // tile-boundary wait: ensure tile t+1 (own loads) landed; barrier makes it all-waves.
        if (t + 1 < nk) {
            if (pf) asm volatile("s_waitcnt vmcnt(6)" ::: "memory");   // keep t+2's 6 in flight
            else    asm volatile("s_waitcnt vmcnt(0)" ::: "memory");   // penultimate tile
        }
        __builtin_amdgcn_s_barrier();
    }

    const int row0 = mt * 256 + wr * 64;
    const int col0 = nt * 128 + wc * 64;
#pragma unroll
    for (int m = 0; m < 4; ++m) {
#pragma unroll
        for (int r = 0; r < 4; ++r) {
            int row = row0 + m * 16 + ((lane >> 4) << 2) + r;
            size_t tok = 0;
            if constexpr (MODE == 1) tok = win_to_tok(row);
#pragma unroll
            for (int n = 0; n < 4; ++n) {
                int col = col0 + n * 16 + (lane & 15);
                float v = acc[m][n][r];
                if constexpr (MODE == 0) {
                    outb[(size_t)row * N + col] = f2b(v);
                } else if constexpr (MODE == 1) {
                    size_t o = tok * 384 + col;
                    outf[o] = resid[o] + v + bias[col];
                } else if constexpr (MODE == 2) {
                    // tanh-form GELU, overflow-safe (err ~3e-4, << bf16 rounding of F)
                    float t2 = v + bias[col];
                    float y  = 0.7978845608028654f * (t2 + 0.044715f * t2 * t2 * t2);
                    float u  = __expf(-2.0f * fabsf(y));
                    float th = (1.f - u) / (1.f + u);
                    outb[(size_t)row * N + col] = f2b(0.5f * t2 * (1.f + copysignf(th, t2)));
                } else {
                    size_t o = (size_t)row * N + col;
                    outf[o] = resid[o] + v + bias[col];
                }
            }
        }
    }
}

// ---------------- attention: one wave per (window, head) ----------------
__global__ __launch_bounds__(64) void attn_kernel(const unsigned short* __restrict__ QKV,
                                                  const int* __restrict__ rel_idx,
                                                  const float* __restrict__ rpb,
                                                  unsigned short* __restrict__ O) {
    __shared__ float Ks[49 * 32];
    __shared__ float Vs[49 * 32];
    int w = blockIdx.x / 12, hd = blockIdx.x - w * 12;
    int lane = threadIdx.x;
    const size_t base = (size_t)w * 49 * 1152;

    for (int i = lane; i < 1568; i += 64) {
        int m = i >> 5, d = i & 31;
        Ks[i] = b2f(QKV[base + (size_t)m * 1152 + 384 + hd * 32 + d]);
        Vs[i] = b2f(QKV[base + (size_t)m * 1152 + 768 + hd * 32 + d]);
    }
    __syncthreads();

    int n = lane < 49 ? lane : 48;
    float q[32];
#pragma unroll
    for (int d = 0; d < 32; ++d)
        q[d] = b2f(QKV[base + (size_t)n * 1152 + hd * 32 + d]) * 0.17677669529663687f;

    int widx = w & 63;
    int wi = widx >> 3, wj = widx & 7;
    auto regionOf = [](int c) { return c < 49 ? 0 : (c < 53 ? 1 : 2); };
    int ti = n / 7, tj = n - (n / 7) * 7;
    int labq = regionOf(wi * 7 + ti) * 3 + regionOf(wj * 7 + tj);

    float sc[49];
    float mx = -1e30f;
#pragma unroll
    for (int m = 0; m < 49; ++m) {
        float s = 0.f;
#pragma unroll
        for (int d = 0; d < 32; ++d) s += q[d] * Ks[m * 32 + d];
        s += rpb[rel_idx[n * 49 + m] * 12 + hd];
        int mi = m / 7, mj = m - (m / 7) * 7;
        int labk = regionOf(wi * 7 + mi) * 3 + regionOf(wj * 7 + mj);
        if (labk != labq) s -= 100.f;
        sc[m] = s;
        mx = fmaxf(mx, s);
    }
    float sum = 0.f;
#pragma unroll
    for (int m = 0; m < 49; ++m) { float e = __expf(sc[m] - mx); sc[m] = e; sum += e; }
    float rinv = 1.f / sum;
    float o[32] = {};
#pragma unroll
    for (int m = 0; m < 49; ++m) {
        float p = sc[m] * rinv;
#pragma unroll
        for (int d = 0; d < 32; ++d) o[d] += p * Vs[m * 32 + d];
    }
    if (lane < 49) {
        unsigned short* op = O + ((size_t)w * 49 + n) * 384 + hd * 32;
#pragma unroll
        for (int d = 0; d < 32; ++d) op[d] = f2b(o[d]);
    }
}

extern "C" void kernel_launch(void* const* d_in, const int* in_sizes, int n_in,
                              void* d_out, int out_size, void* d_ws, size_t ws_size,
                              hipStream_t stream) {
    const float* x     = (const float*)d_in[0];
    const int*   rel   = (const int*)  d_in[3];
    const float* rpb   = (const float*)d_in[4];
    const float* qkvw  = (const float*)d_in[5];
    const float* projw = (const float*)d_in[6];
    const float* projb = (const float*)d_in[7];
    const float* n1g   = (const float*)d_in[8];
    const float* n1b   = (const float*)d_in[9];
    const float* n2g   = (const float*)d_in[10];
    const float* n2b   = (const float*)d_in[11];
    const float* w1    = (const float*)d_in[12];
    const float* b1    = (const float*)d_in[13];
    const float* w2    = (const float*)d_in[14];
    const float* b2    = (const float*)d_in[15];
    float* out = (float*)d_out;

    const int T = in_sizes[0] / 384;   // 100352 = 256 * 392

    // ---- workspace layout (Hh lives in d_out) ----
    char* ws = (char*)d_ws;
    size_t off = 0;
    auto alloc = [&](size_t bytes) {
        char* p = ws + off;
        off += (bytes + 255) & ~(size_t)255;
        return p;
    };
    unsigned short* WqT = (unsigned short*)alloc((size_t)1152 * 384 * 2);
    unsigned short* WpT = (unsigned short*)alloc((size_t)384 * 384 * 2);
    unsigned short* W1T = (unsigned short*)alloc((size_t)1536 * 384 * 2);
    unsigned short* W2T = (unsigned short*)alloc((size_t)384 * 1536 * 2);
    unsigned short* slotA = (unsigned short*)alloc((size_t)T * 384 * 2);   // X1 -> O -> X2
    unsigned short* slotB = (unsigned short*)alloc((size_t)T * 1536 * 2);  // QKV -> F

    unsigned short* X1  = slotA;
    unsigned short* O   = slotA;
    unsigned short* X2  = slotA;
    unsigned short* QKV = slotB;
    unsigned short* F   = slotB;
    float*          Hh  = out;

    wprep<<<dim3((1152 * 384 + 255) / 256), 256, 0, stream>>>(qkvw, WqT, 384, 1152);
    wprep<<<dim3((384 * 384 + 255) / 256),  256, 0, stream>>>(projw, WpT, 384, 384);
    wprep<<<dim3((384 * 1536 + 255) / 256), 256, 0, stream>>>(w1, W1T, 384, 1536);
    wprep<<<dim3((1536 * 384 + 255) / 256), 256, 0, stream>>>(w2, W2T, 1536, 384);

    const int MT = T / 256;   // 392 M-tiles

    // LN1 + shifted-window gather -> X1 (bf16, window-token order)
    ln_kernel<1><<<dim3(T / 4), 256, 0, stream>>>(x, n1g, n1b, X1, T);
    // QKV projection
    gemm_kernel<0><<<dim3(MT * (1152 / 128)), 512, 0, stream>>>(
        X1, WqT, T, 1152, 384, nullptr, nullptr, QKV, nullptr);
    // windowed attention (reads QKV/slotB, writes O/slotA)
    attn_kernel<<<dim3((T / 49) * 12), 64, 0, stream>>>(QKV, rel, rpb, O);
    // proj + bias + un-window/un-roll + residual -> Hh (= d_out, fp32)
    gemm_kernel<1><<<dim3(MT * (384 / 128)), 512, 0, stream>>>(
        O, WpT, T, 384, 384, projb, x, nullptr, Hh);
    // LN2 -> X2 (bf16, overwrites slotA)
    ln_kernel<0><<<dim3(T / 4), 256, 0, stream>>>(Hh, n2g, n2b, X2, T);
    // FFN1 + bias + GELU -> F (bf16, overwrites slotB)
    gemm_kernel<2><<<dim3(MT * (1536 / 128)), 512, 0, stream>>>(
        X2, W1T, T, 1536, 384, b1, nullptr, F, nullptr);
    // FFN2 + bias + residual -> out (fp32, in-place RMW on d_out)
    gemm_kernel<3><<<dim3(MT * (384 / 128)), 512, 0, stream>>>(
        F, W2T, T, 384, 1536, b2, Hh, nullptr, out);
}

// Round 9
// 1197.924 us; speedup vs baseline: 1.0939x; 1.0939x over previous
//
#include <hip/hip_runtime.h>

#define DEV __device__ __forceinline__

typedef __bf16 bf16x8 __attribute__((ext_vector_type(8)));
typedef float  f32x4  __attribute__((ext_vector_type(4)));

DEV float b2f(unsigned short u) {
    unsigned int t = ((unsigned int)u) << 16;
    return __uint_as_float(t);
}
DEV unsigned short f2b(float f) {
    unsigned int u = __float_as_uint(f);
    unsigned int r = (u + 0x7FFFu + ((u >> 16) & 1u)) >> 16;
    return (unsigned short)r;
}

DEV void gload_lds16(const unsigned short* g, void* l) {
    __builtin_amdgcn_global_load_lds(
        (const __attribute__((address_space(1))) void*)(const void*)g,
        (__attribute__((address_space(3))) void*)l, 16, 0, 0);
}

// dest window-row -> source/dest token index (roll by SS=3, window 7x7, 56x56, 64 win/batch)
DEV size_t win_to_tok(int row) {
    int w = row / 49, t = row - w * 49;
    int b  = w >> 6, widx = w & 63;
    int wi = widx >> 3, wj = widx & 7;
    int ti = t / 7, tj = t - ti * 7;
    int hh = wi * 7 + ti + 3; if (hh >= 56) hh -= 56;
    int ww = wj * 7 + tj + 3; if (ww >= 56) ww -= 56;
    return (size_t)b * 3136 + (size_t)hh * 56 + ww;
}

// ---------------- weight prep: fp32 [K][N] -> bf16 [N][K] ----------------
__global__ void wprep(const float* __restrict__ src, unsigned short* __restrict__ dst,
                      int K, int N) {
    int idx = blockIdx.x * 256 + threadIdx.x;
    if (idx >= K * N) return;
    int k = idx / N, n = idx - k * N;
    dst[(size_t)n * K + k] = f2b(src[idx]);
}

// ---------------- LayerNorm (+optional shifted-window gather), fp32 -> bf16 ----------------
template <int REMAP>
__global__ __launch_bounds__(256) void ln_kernel(const float* __restrict__ x,
                                                 const float* __restrict__ g,
                                                 const float* __restrict__ b,
                                                 unsigned short* __restrict__ out,
                                                 int rows) {
    int r = blockIdx.x * 4 + (threadIdx.x >> 6);
    int lane = threadIdx.x & 63;
    if (r >= rows) return;
    size_t src = REMAP ? win_to_tok(r) : (size_t)r;
    const float* xp = x + src * 384;
    float v[6];
    float s = 0.f;
#pragma unroll
    for (int i = 0; i < 6; ++i) { v[i] = xp[i * 64 + lane]; s += v[i]; }
#pragma unroll
    for (int off = 32; off; off >>= 1) s += __shfl_xor(s, off, 64);
    float mu = s * (1.f / 384.f);
    float q = 0.f;
#pragma unroll
    for (int i = 0; i < 6; ++i) { float d = v[i] - mu; q += d * d; }
#pragma unroll
    for (int off = 32; off; off >>= 1) q += __shfl_xor(q, off, 64);
    float inv = rsqrtf(q * (1.f / 384.f) + 1e-5f);
    unsigned short* op = out + (size_t)r * 384;
#pragma unroll
    for (int i = 0; i < 6; ++i) {
        int c = i * 64 + lane;
        op[c] = f2b((v[i] - mu) * inv * g[c] + b[c]);
    }
}

// ---------------- GEMM (R7-best config): 128x128 tile, (DEPTH+1)-buffer LDS ring ----------------
// MODE 0: out bf16 = C                               (QKV)
// MODE 1: h[tok] = x[tok] + C + bias  (un-window+un-roll remap, fp32 out)   (proj)
template <int MODE, int DEPTH, int MINW>
__global__ __launch_bounds__(256, MINW) void gemm_kernel(const unsigned short* __restrict__ A,
                                                         const unsigned short* __restrict__ Bt,
                                                         int M, int N, int K,
                                                         const float* __restrict__ bias,
                                                         const float* __restrict__ resid,
                                                         unsigned short* __restrict__ outb,
                                                         float* __restrict__ outf) {
    constexpr int NBUF = DEPTH + 1;
    __shared__ unsigned short As[NBUF][128 * 32];
    __shared__ unsigned short Bs[NBUF][128 * 32];
    const int tid = threadIdx.x;
    const int wid = tid >> 6, lane = tid & 63;
    const int ntile = N >> 7;

    int bid = blockIdx.x;
    int nwg = gridDim.x;
    int swb = ((nwg & 7) == 0) ? ((bid & 7) * (nwg >> 3) + (bid >> 3)) : bid;
    const int mt = swb / ntile, nt = swb - mt * ntile;
    const int wr = wid >> 1, wc = wid & 1;

    f32x4 acc[4][4] = {};

    const int rA   = lane >> 2;
    const int kofs = (((lane & 3) ^ ((lane >> 3) & 3)) << 3);
    const unsigned short* Abase = A  + (size_t)(mt * 128) * K;
    const unsigned short* Bbase = Bt + (size_t)(nt * 128) * K;

    auto stage = [&](int buf, int k0) {
#pragma unroll
        for (int j = 0; j < 2; ++j) {
            int c = wid * 2 + j;
            gload_lds16(Abase + (size_t)(c * 16 + rA) * K + k0 + kofs, &As[buf][c * 512]);
            gload_lds16(Bbase + (size_t)(c * 16 + rA) * K + k0 + kofs, &Bs[buf][c * 512]);
        }
    };

    const int sr  = ((lane & 15) >> 1) & 3;
    const int cbA = (((lane >> 4) ^ sr) << 3);
    const int rowA = wr * 64 + (lane & 15);
    const int rowB = wc * 64 + (lane & 15);

    const int nk = K >> 5;
    stage(0, 0);
    if (DEPTH >= 2 && nk > 1) stage(1, 32);
    if (DEPTH >= 3 && nk > 2) stage(2, 64);

    for (int t = 0; t < nk; ++t) {
        const int cur = t % NBUF;
        if (t + DEPTH < nk) {
            stage((t + DEPTH) % NBUF, (t + DEPTH) << 5);
            if constexpr (DEPTH == 1) {
                asm volatile("s_waitcnt vmcnt(4)" ::: "memory");
            } else {
                asm volatile("s_waitcnt vmcnt(12)" ::: "memory");
            }
        } else if (DEPTH >= 3 && t + 2 < nk) {
            asm volatile("s_waitcnt vmcnt(8)" ::: "memory");
        } else if (t + 1 < nk) {
            asm volatile("s_waitcnt vmcnt(4)" ::: "memory");
        } else {
            asm volatile("s_waitcnt vmcnt(0)" ::: "memory");
        }
        __builtin_amdgcn_s_barrier();

        bf16x8 a[4], b[4];
#pragma unroll
        for (int m = 0; m < 4; ++m)
            a[m] = *(const bf16x8*)&As[cur][(rowA + m * 16) * 32 + cbA];
#pragma unroll
        for (int n = 0; n < 4; ++n)
            b[n] = *(const bf16x8*)&Bs[cur][(rowB + n * 16) * 32 + cbA];
#pragma unroll
        for (int m = 0; m < 4; ++m)
#pragma unroll
            for (int n = 0; n < 4; ++n)
                acc[m][n] = __builtin_amdgcn_mfma_f32_16x16x32_bf16(a[m], b[n], acc[m][n], 0, 0, 0);

        asm volatile("s_waitcnt lgkmcnt(0)" ::: "memory");
        __builtin_amdgcn_s_barrier();
    }

    const int row0 = mt * 128 + wr * 64;
    const int col0 = nt * 128 + wc * 64;
#pragma unroll
    for (int m = 0; m < 4; ++m) {
#pragma unroll
        for (int r = 0; r < 4; ++r) {
            int row = row0 + m * 16 + ((lane >> 4) << 2) + r;
            size_t tok = 0;
            if constexpr (MODE == 1) tok = win_to_tok(row);
#pragma unroll
            for (int n = 0; n < 4; ++n) {
                int col = col0 + n * 16 + (lane & 15);
                float v = acc[m][n][r];
                if constexpr (MODE == 0) {
                    outb[(size_t)row * N + col] = f2b(v);
                } else {
                    size_t o = tok * 384 + col;
                    outf[o] = resid[o] + v + bias[col];
                }
            }
        }
    }
}

// ---------------- fused LN2 + FFN1(GELU) + FFN2 + residual ----------------
// Block = 128 tokens, 512 threads (8 waves as 2M x 4N). Per block:
//  A) LN2 rows -> X2s LDS [128][384] bf16 (chunk-XOR swizzle)
//  B) per F-chunk c (12 x 128 cols): F = X2s @ W1T-tile (B staged 8KB dbuf, vmcnt(1));
//     GELU -> Fs LDS [128][128] bf16 (swizzled)
//  C) out_acc[128x384] += Fs @ W2T-tile (B staged 24KB single-buffer)
//  Epilogue: out = Hh + out_acc + b2   (out aliases Hh; row-exclusive per block)
__global__ __launch_bounds__(512, 2) void ffn_kernel(const float* __restrict__ Hh,
                                                     const float* __restrict__ g2,
                                                     const float* __restrict__ bn2,
                                                     const unsigned short* __restrict__ W1T,
                                                     const float* __restrict__ bias1,
                                                     const unsigned short* __restrict__ W2T,
                                                     const float* __restrict__ bias2,
                                                     float* __restrict__ out) {
    __shared__ char lds_raw[98304 + 32768 + 24576];   // X2s | Fs | Bst = 152 KB
    char* X2s = lds_raw;
    char* Fs  = lds_raw + 98304;
    char* Bst = lds_raw + 98304 + 32768;

    const int tid = threadIdx.x;
    const int wid = tid >> 6, lane = tid & 63;
    const int wr2 = wid >> 2;        // 0..1  (64-row half)
    const int wc4 = wid & 3;         // 0..3  (col group)
    const int row0 = blockIdx.x * 128;

    // ---- Phase A: LN2 -> X2s ----
    float gv[6], bv[6];
#pragma unroll
    for (int i = 0; i < 6; ++i) { gv[i] = g2[i * 64 + lane]; bv[i] = bn2[i * 64 + lane]; }
    for (int rr = 0; rr < 16; ++rr) {
        int row = wid * 16 + rr;
        const float* xp = Hh + (size_t)(row0 + row) * 384;
        float v[6];
        float s = 0.f;
#pragma unroll
        for (int i = 0; i < 6; ++i) { v[i] = xp[i * 64 + lane]; s += v[i]; }
#pragma unroll
        for (int off = 32; off; off >>= 1) s += __shfl_xor(s, off, 64);
        float mu = s * (1.f / 384.f);
        float q = 0.f;
#pragma unroll
        for (int i = 0; i < 6; ++i) { float d = v[i] - mu; q += d * d; }
#pragma unroll
        for (int off = 32; off; off >>= 1) q += __shfl_xor(q, off, 64);
        float inv = rsqrtf(q * (1.f / 384.f) + 1e-5f);
#pragma unroll
        for (int i = 0; i < 6; ++i) {
            int c = i * 64 + lane;
            int phys = (c >> 3) ^ (row & 7);
            *(unsigned short*)&X2s[row * 768 + phys * 16 + (c & 7) * 2] =
                f2b((v[i] - mu) * inv * gv[i] + bv[i]);
        }
    }
    __syncthreads();

    f32x4 oacc[4][6] = {};
    const int fr = lane & 15;        // fragment row-in-16
    const int kq = lane >> 4;        // k-quarter 0..3

    // staging helpers (linear LDS dest, pre-swizzled global k-chunk)
    const int brow = tid >> 2;                 // 0..127
    const int gkc  = (tid & 3) ^ (brow & 3);   // pre-swizzled chunk within 32-k
    auto stageB1 = [&](int buf, int c, int s) {
        gload_lds16(W1T + (size_t)(c * 128 + brow) * 384 + s * 32 + gkc * 8,
                    Bst + buf * 8192 + tid * 16);
    };
    auto stageB2 = [&](int c, int s) {
#pragma unroll
        for (int j = 0; j < 3; ++j) {
            int r2 = 128 * j + brow;
            int gk = (tid & 3) ^ (r2 & 3);
            gload_lds16(W2T + (size_t)r2 * 1536 + c * 128 + s * 32 + gk * 8,
                        Bst + j * 8192 + tid * 16);
        }
    };

    for (int c = 0; c < 12; ++c) {
        // ---- Phase B: F_chunk = X2s @ W1T-tile ----
        f32x4 facc[4][2] = {};
        stageB1(0, c, 0);
        for (int s = 0; s < 12; ++s) {
            if (s + 1 < 12) {
                stageB1((s + 1) & 1, c, s + 1);
                asm volatile("s_waitcnt vmcnt(1)" ::: "memory");
            } else {
                asm volatile("s_waitcnt vmcnt(0)" ::: "memory");
            }
            __builtin_amdgcn_s_barrier();
            bf16x8 af[4], bf[2];
#pragma unroll
            for (int m = 0; m < 4; ++m) {
                int row = wr2 * 64 + m * 16 + fr;
                int phys = (s * 4 + kq) ^ (row & 7);
                af[m] = *(const bf16x8*)&X2s[row * 768 + phys * 16];
            }
#pragma unroll
            for (int n = 0; n < 2; ++n) {
                int row = wc4 * 32 + n * 16 + fr;
                int phys = kq ^ (row & 3);
                bf[n] = *(const bf16x8*)&Bst[((s & 1) * 8192) + row * 64 + phys * 16];
            }
            asm volatile("s_waitcnt lgkmcnt(0)" ::: "memory");
            __builtin_amdgcn_sched_barrier(0);
            __builtin_amdgcn_s_setprio(1);
#pragma unroll
            for (int m = 0; m < 4; ++m)
#pragma unroll
                for (int n = 0; n < 2; ++n)
                    facc[m][n] = __builtin_amdgcn_mfma_f32_16x16x32_bf16(af[m], bf[n], facc[m][n], 0, 0, 0);
            __builtin_amdgcn_s_setprio(0);
            __builtin_amdgcn_s_barrier();
        }

        // ---- GELU -> Fs (bf16, swizzled) ----
#pragma unroll
        for (int m = 0; m < 4; ++m)
#pragma unroll
            for (int n = 0; n < 2; ++n)
#pragma unroll
                for (int r = 0; r < 4; ++r) {
                    int row = wr2 * 64 + m * 16 + kq * 4 + r;
                    int col = wc4 * 32 + n * 16 + fr;
                    float t2 = facc[m][n][r] + bias1[c * 128 + col];
                    float y  = 0.7978845608028654f * (t2 + 0.044715f * t2 * t2 * t2);
                    float u  = __expf(-2.0f * fabsf(y));
                    float th = (1.f - u) / (1.f + u);
                    float fv = 0.5f * t2 * (1.f + copysignf(th, t2));
                    int phys = (col >> 3) ^ (row & 7);
                    *(unsigned short*)&Fs[row * 256 + phys * 16 + (col & 7) * 2] = f2b(fv);
                }
        __syncthreads();   // Fs visible + Bst reads retired block-wide

        // ---- Phase C: out_acc += Fs @ W2T-tile ----
        for (int s = 0; s < 4; ++s) {
            stageB2(c, s);
            asm volatile("s_waitcnt vmcnt(0)" ::: "memory");
            __builtin_amdgcn_s_barrier();
            bf16x8 ac[4], bc[6];
#pragma unroll
            for (int m = 0; m < 4; ++m) {
                int row = wr2 * 64 + m * 16 + fr;
                int phys = (s * 4 + kq) ^ (row & 7);
                ac[m] = *(const bf16x8*)&Fs[row * 256 + phys * 16];
            }
#pragma unroll
            for (int n = 0; n < 6; ++n) {
                int row = wc4 * 96 + n * 16 + fr;
                int phys = kq ^ (row & 3);
                bc[n] = *(const bf16x8*)&Bst[row * 64 + phys * 16];
            }
            asm volatile("s_waitcnt lgkmcnt(0)" ::: "memory");
            __builtin_amdgcn_sched_barrier(0);
            __builtin_amdgcn_s_setprio(1);
#pragma unroll
            for (int m = 0; m < 4; ++m)
#pragma unroll
                for (int n = 0; n < 6; ++n)
                    oacc[m][n] = __builtin_amdgcn_mfma_f32_16x16x32_bf16(ac[m], bc[n], oacc[m][n], 0, 0, 0);
            __builtin_amdgcn_s_setprio(0);
            __builtin_amdgcn_s_barrier();   // Bst may be overwritten next step
        }
    }

    // ---- Epilogue: out = Hh + acc + b2 ----
#pragma unroll
    for (int m = 0; m < 4; ++m)
#pragma unroll
        for (int r = 0; r < 4; ++r) {
            int row = row0 + wr2 * 64 + m * 16 + kq * 4 + r;
#pragma unroll
            for (int n = 0; n < 6; ++n) {
                int col = wc4 * 96 + n * 16 + fr;
                size_t o = (size_t)row * 384 + col;
                out[o] = out[o] + oacc[m][n][r] + bias2[col];
            }
        }
}

// ---------------- attention: one wave per (window, head) ----------------
__global__ __launch_bounds__(64) void attn_kernel(const unsigned short* __restrict__ QKV,
                                                  const int* __restrict__ rel_idx,
                                                  const float* __restrict__ rpb,
                                                  unsigned short* __restrict__ O) {
    __shared__ float Ks[49 * 32];
    __shared__ float Vs[49 * 32];
    int w = blockIdx.x / 12, hd = blockIdx.x - w * 12;
    int lane = threadIdx.x;
    const size_t base = (size_t)w * 49 * 1152;

    for (int i = lane; i < 1568; i += 64) {
        int m = i >> 5, d = i & 31;
        Ks[i] = b2f(QKV[base + (size_t)m * 1152 + 384 + hd * 32 + d]);
        Vs[i] = b2f(QKV[base + (size_t)m * 1152 + 768 + hd * 32 + d]);
    }
    __syncthreads();

    int n = lane < 49 ? lane : 48;
    float q[32];
#pragma unroll
    for (int d = 0; d < 32; ++d)
        q[d] = b2f(QKV[base + (size_t)n * 1152 + hd * 32 + d]) * 0.17677669529663687f;

    int widx = w & 63;
    int wi = widx >> 3, wj = widx & 7;
    auto regionOf = [](int c) { return c < 49 ? 0 : (c < 53 ? 1 : 2); };
    int ti = n / 7, tj = n - (n / 7) * 7;
    int labq = regionOf(wi * 7 + ti) * 3 + regionOf(wj * 7 + tj);

    float sc[49];
    float mx = -1e30f;
#pragma unroll
    for (int m = 0; m < 49; ++m) {
        float s = 0.f;
#pragma unroll
        for (int d = 0; d < 32; ++d) s += q[d] * Ks[m * 32 + d];
        s += rpb[rel_idx[n * 49 + m] * 12 + hd];
        int mi = m / 7, mj = m - (m / 7) * 7;
        int labk = regionOf(wi * 7 + mi) * 3 + regionOf(wj * 7 + mj);
        if (labk != labq) s -= 100.f;
        sc[m] = s;
        mx = fmaxf(mx, s);
    }
    float sum = 0.f;
#pragma unroll
    for (int m = 0; m < 49; ++m) { float e = __expf(sc[m] - mx); sc[m] = e; sum += e; }
    float rinv = 1.f / sum;
    float o[32] = {};
#pragma unroll
    for (int m = 0; m < 49; ++m) {
        float p = sc[m] * rinv;
#pragma unroll
        for (int d = 0; d < 32; ++d) o[d] += p * Vs[m * 32 + d];
    }
    if (lane < 49) {
        unsigned short* op = O + ((size_t)w * 49 + n) * 384 + hd * 32;
#pragma unroll
        for (int d = 0; d < 32; ++d) op[d] = f2b(o[d]);
    }
}

extern "C" void kernel_launch(void* const* d_in, const int* in_sizes, int n_in,
                              void* d_out, int out_size, void* d_ws, size_t ws_size,
                              hipStream_t stream) {
    const float* x     = (const float*)d_in[0];
    const int*   rel   = (const int*)  d_in[3];
    const float* rpb   = (const float*)d_in[4];
    const float* qkvw  = (const float*)d_in[5];
    const float* projw = (const float*)d_in[6];
    const float* projb = (const float*)d_in[7];
    const float* n1g   = (const float*)d_in[8];
    const float* n1b   = (const float*)d_in[9];
    const float* n2g   = (const float*)d_in[10];
    const float* n2b   = (const float*)d_in[11];
    const float* w1    = (const float*)d_in[12];
    const float* b1    = (const float*)d_in[13];
    const float* w2    = (const float*)d_in[14];
    const float* b2    = (const float*)d_in[15];
    float* out = (float*)d_out;

    const int T = in_sizes[0] / 384;   // 100352

    char* ws = (char*)d_ws;
    size_t off = 0;
    auto alloc = [&](size_t bytes) {
        char* p = ws + off;
        off += (bytes + 255) & ~(size_t)255;
        return p;
    };
    unsigned short* WqT = (unsigned short*)alloc((size_t)1152 * 384 * 2);
    unsigned short* WpT = (unsigned short*)alloc((size_t)384 * 384 * 2);
    unsigned short* W1T = (unsigned short*)alloc((size_t)1536 * 384 * 2);
    unsigned short* W2T = (unsigned short*)alloc((size_t)384 * 1536 * 2);
    unsigned short* slotA = (unsigned short*)alloc((size_t)T * 384 * 2);   // X1 -> O
    unsigned short* slotB = (unsigned short*)alloc((size_t)T * 1152 * 2);  // QKV

    unsigned short* X1  = slotA;
    unsigned short* O   = slotA;
    unsigned short* QKV = slotB;
    float*          Hh  = out;

    wprep<<<dim3((1152 * 384 + 255) / 256), 256, 0, stream>>>(qkvw, WqT, 384, 1152);
    wprep<<<dim3((384 * 384 + 255) / 256),  256, 0, stream>>>(projw, WpT, 384, 384);
    wprep<<<dim3((384 * 1536 + 255) / 256), 256, 0, stream>>>(w1, W1T, 384, 1536);
    wprep<<<dim3((1536 * 384 + 255) / 256), 256, 0, stream>>>(w2, W2T, 1536, 384);

    // LN1 + shifted-window gather -> X1 (bf16, window-token order)
    ln_kernel<1><<<dim3(T / 4), 256, 0, stream>>>(x, n1g, n1b, X1, T);
    // QKV projection (R7-best: depth-1, reg-capped)
    gemm_kernel<0, 1, 4><<<dim3((T / 128) * (1152 / 128)), 256, 0, stream>>>(
        X1, WqT, T, 1152, 384, nullptr, nullptr, QKV, nullptr);
    // windowed attention
    attn_kernel<<<dim3((T / 49) * 12), 64, 0, stream>>>(QKV, rel, rpb, O);
    // proj + bias + un-window/un-roll + residual -> Hh (= d_out, fp32)
    gemm_kernel<1, 1, 4><<<dim3((T / 128) * (384 / 128)), 256, 0, stream>>>(
        O, WpT, T, 384, 384, projb, x, nullptr, Hh);
    // fused LN2 + FFN1(GELU) + FFN2 + residual (in-place on d_out)
    ffn_kernel<<<dim3(T / 128), 512, 0, stream>>>(
        Hh, n2g, n2b, W1T, b1, W2T, b2, out);
}